// Round 3
// baseline (240.894 us; speedup 1.0000x reference)
//
#include <hip/hip_runtime.h>
#include <stdint.h>

// RNN: h_t = tanh(x_t W_ih^T + b_ih + b_hh + h_{t-1} W_hh^T)
// out[b,t] = W_fc . h_t + b_fc ;  hidden = h_T.  B=8192, T=512, I=H=7. fp32.
//
// R9: wave specialization, defensive rebuild. R7/R8 both aborted; common to
// both (vs passing R6) was the inline-asm prefetch (112 asm-tied VGPRs +
// vmcnt counting + tight launch_bounds). This version removes ALL inline asm:
// plain float4 loads in the helper; one memory latency amortized per 8-step
// chunk; the rec wave on the same SIMD hides the helper's stalls (TLP).
//  - 512-thread block = 8 waves: waves 0-3 recurrence (pairs 0-3),
//    waves 4-7 helper (pairs 0-3). Round-robin wave->SIMD puts one rec +
//    one helper wave per SIMD. 32 chains/block, 256 blocks, 1 block/CU.
//  - 65 uniform top-level __syncthreads (1 prologue + 64 slots).
//  - u/h parity double-buffered in LDS; every RAW/WAR barrier-separated.
// Slot t: rec computes h(t) from u(t); helper loads x(t+1), emits out(t-1),
// writes u(t+1).

#define B_TOTAL 8192
#define T_STEPS 512

#define DPP_QUAD0 0x00        // quad_perm [0,0,0,0]
#define DPP_QUAD1 0x55        // quad_perm [1,1,1,1]
#define DPP_QUAD2 0xAA        // quad_perm [2,2,2,2]
#define DPP_QUAD3 0xFF        // quad_perm [3,3,3,3]
#define DPP_XOR1  0xB1        // quad_perm [1,0,3,2]
#define DPP_XOR2  0x4E        // quad_perm [2,3,0,1]
#define DPP_HM    0x141       // row_half_mirror

template <int CTRL>
__device__ __forceinline__ float dpp_mov(float v) {
    int s = __float_as_int(v);
    return __int_as_float(__builtin_amdgcn_update_dpp(s, s, CTRL, 0xF, 0xF, true));
}

__device__ __forceinline__ float tanh_fast(float a) {
    float e = __builtin_amdgcn_exp2f(a * 2.8853900817779268f);
    float r = __builtin_amdgcn_rcpf(e + 1.0f);
    return __builtin_fmaf(-2.0f, r, 1.0f);
}

__global__ __launch_bounds__(512, 2) void rnn_kernel(
    const float* __restrict__ x,    // [B, T, I]
    const float* __restrict__ Wih,  // [H, I]
    const float* __restrict__ Whh,  // [H, H]
    const float* __restrict__ bih,  // [H]
    const float* __restrict__ bhh,  // [H]
    const float* __restrict__ Wfc,  // [1, H]
    const float* __restrict__ bfc,  // [1]
    float* __restrict__ out)        // [B*T] out, then [B*H] hidden
{
    const int tid   = threadIdx.x;
    const int wid   = tid >> 6;         // wave id 0..7
    const int role  = wid >> 2;         // 0 = recurrence (w0-3), 1 = helper (w4-7)
    const int pair  = wid & 3;          // chain-group 0..3
    const int lane  = tid & 63;
    const int k     = lane & 7;         // h-row (7 = dummy)
    const int b     = blockIdx.x * 32 + pair * 8 + (lane >> 3);
    const int lbase = lane * 10;        // stride 10 floats: 8B-aligned, mild banks

    // [parity][pair][lane*10 + s]; 20480 B each, 40960 B total.
    __shared__ __attribute__((aligned(16))) float lds_u[2][4][640];
    __shared__ __attribute__((aligned(16))) float lds_h[2][4][640];

    // ---- per-role persistent state ----
    float wa[4] = {0.f, 0.f, 0.f, 0.f}, wb[4] = {0.f, 0.f, 0.f, 0.f};
    float ra0 = 0.f, ra1 = 0.f, ra2 = 0.f, ra3 = 0.f;
    float rb0 = 0.f, rb1 = 0.f, rb2 = 0.f, rb3 = 0.f;
    float wih[7] = {0.f, 0.f, 0.f, 0.f, 0.f, 0.f, 0.f};
    float bias = 0.f, wfc_own = 0.f, bfcv = 0.f;
    const float* xrow = x + (size_t)b * (T_STEPS * 7);   // 3584 floats, 16B-aligned
    float* outp = out + (size_t)b * T_STEPS;

    // Compute u from 56 loaded floats, store to lds_u[par].
    auto u_store = [&](const float4* xb, int par) {
        float xv[56];
        #pragma unroll
        for (int i = 0; i < 14; ++i) {
            xv[4 * i + 0] = xb[i].x; xv[4 * i + 1] = xb[i].y;
            xv[4 * i + 2] = xb[i].z; xv[4 * i + 3] = xb[i].w;
        }
        float u[8];
        #pragma unroll
        for (int s = 0; s < 8; ++s) {
            const float* xs = &xv[s * 7];
            float p01 = __builtin_fmaf(wih[1], xs[1], wih[0] * xs[0]);
            float p23 = __builtin_fmaf(wih[3], xs[3], wih[2] * xs[2]);
            float p45 = __builtin_fmaf(wih[5], xs[5], wih[4] * xs[4]);
            float p6b = __builtin_fmaf(wih[6], xs[6], bias);
            u[s] = (p01 + p23) + (p45 + p6b);
        }
        float2* up = (float2*)&lds_u[par][pair][lbase];
        up[0] = make_float2(u[0], u[1]);
        up[1] = make_float2(u[2], u[3]);
        up[2] = make_float2(u[4], u[5]);
        up[3] = make_float2(u[6], u[7]);
    };

    // Out-projection butterfly for chunk t from lds_h, store 8 outputs.
    auto emit_out = [&](int t) {
        const float2* hp = (const float2*)&lds_h[t & 1][pair][lbase];
        float2 h01 = hp[0], h23 = hp[1], h45 = hp[2], h67 = hp[3];
        float hs[8] = {h01.x, h01.y, h23.x, h23.y, h45.x, h45.y, h67.x, h67.y};
        float o[8];
        #pragma unroll
        for (int s = 0; s < 8; ++s) {
            float v = wfc_own * hs[s];
            v += dpp_mov<DPP_XOR1>(v);
            v += dpp_mov<DPP_XOR2>(v);
            v += dpp_mov<DPP_HM>(v);
            o[s] = v + bfcv;
        }
        if (k == 7) {
            *(float4*)(outp + t * 8 + 0) = make_float4(o[0], o[1], o[2], o[3]);
            *(float4*)(outp + t * 8 + 4) = make_float4(o[4], o[5], o[6], o[7]);
        }
    };

    // 8-step serial recurrence on lds_u[par] -> lds_h[par].
    auto rec_step = [&](int par) {
        const float2* up = (const float2*)&lds_u[par][pair][lbase];
        float2 u01 = up[0], u23 = up[1], u45 = up[2], u67 = up[3];
        float u[8] = {u01.x, u01.y, u23.x, u23.y, u45.x, u45.y, u67.x, u67.y};
        float hs[8];
        #pragma unroll
        for (int s = 0; s < 8; ++s) {
            float p0 = __builtin_fmaf(wa[0], ra0, u[s]);
            float p1 = __builtin_fmaf(wa[2], ra2, wa[1] * ra1);
            float p2 = __builtin_fmaf(wb[0], rb0, wa[3] * ra3);
            float p3 = __builtin_fmaf(wb[2], rb2, wb[1] * rb1);
            float p4 = wb[3] * rb3;
            float acc = (p0 + p1) + (p2 + (p3 + p4));
            float hk = tanh_fast(acc);
            hs[s] = hk;
            ra0 = dpp_mov<DPP_QUAD0>(hk);
            ra1 = dpp_mov<DPP_QUAD1>(hk);
            ra2 = dpp_mov<DPP_QUAD2>(hk);
            ra3 = dpp_mov<DPP_QUAD3>(hk);
            rb0 = dpp_mov<DPP_HM>(ra0);
            rb1 = dpp_mov<DPP_HM>(ra1);
            rb2 = dpp_mov<DPP_HM>(ra2);
            rb3 = dpp_mov<DPP_HM>(ra3);
        }
        float2* hp = (float2*)&lds_h[par][pair][lbase];
        hp[0] = make_float2(hs[0], hs[1]);
        hp[1] = make_float2(hs[2], hs[3]);
        hp[2] = make_float2(hs[4], hs[5]);
        hp[3] = make_float2(hs[6], hs[7]);
    };

    // ---- role-divergent prologue (no barriers inside) ----
    if (role == 0) {
        const int quad = (lane >> 2) & 1;
        float whh_row[8];
        #pragma unroll
        for (int i = 0; i < 8; ++i) whh_row[i] = 0.0f;
        if (k < 7) {
            #pragma unroll
            for (int i = 0; i < 7; ++i) whh_row[i] = Whh[k * 7 + i];
        }
        #pragma unroll
        for (int j = 0; j < 4; ++j) {
            wa[j] = quad ? whh_row[4 + j] : whh_row[j];
            wb[j] = quad ? whh_row[j]     : whh_row[4 + j];
        }
    } else {
        if (k < 7) {
            #pragma unroll
            for (int i = 0; i < 7; ++i) wih[i] = Wih[k * 7 + i];
            bias = bih[k] + bhh[k];
            wfc_own = Wfc[k];
        }
        bfcv = bfc[0];
        float4 xb[14];
        const float4* src = (const float4*)xrow;        // chunk 0
        #pragma unroll
        for (int i = 0; i < 14; ++i) xb[i] = src[i];
        u_store(xb, 0);                                 // u(0) -> parity 0
    }
    __syncthreads();                                    // b0: u(0) ready

    // Slot t: rec computes h(t); helper loads x(t+1), emits out(t-1),
    // writes u(t+1). One uniform barrier per slot.
    #pragma unroll 1
    for (int t = 0; t < 64; ++t) {
        if (role == 0) {
            rec_step(t & 1);
        } else {
            float4 xb[14];
            if (t < 63) {
                const float4* src = (const float4*)(xrow + (t + 1) * 56);
                #pragma unroll
                for (int i = 0; i < 14; ++i) xb[i] = src[i];
            }
            if (t > 0) emit_out(t - 1);     // independent of the loads above
            if (t < 63) u_store(xb, (t + 1) & 1);
        }
        __syncthreads();
    }

    // ---- epilogue (after final barrier; no more barriers) ----
    if (role == 0) {
        // hidden h_T: lane k's own value is ra_{k&3} (both quads)
        if (k < 7) {
            int kk = k & 3;
            float hv = (kk == 0) ? ra0 : (kk == 1) ? ra1 : (kk == 2) ? ra2 : ra3;
            out[(size_t)B_TOTAL * T_STEPS + (size_t)b * 7 + k] = hv;
        }
    } else {
        emit_out(63);                       // h(63) written before final barrier
    }
}

extern "C" void kernel_launch(void* const* d_in, const int* in_sizes, int n_in,
                              void* d_out, int out_size, void* d_ws, size_t ws_size,
                              hipStream_t stream) {
    const float* x   = (const float*)d_in[0];
    const float* Wih = (const float*)d_in[1];
    const float* Whh = (const float*)d_in[2];
    const float* bih = (const float*)d_in[3];
    const float* bhh = (const float*)d_in[4];
    const float* Wfc = (const float*)d_in[5];
    const float* bfc = (const float*)d_in[6];
    float* out = (float*)d_out;

    // 32 chains/block (4 rec + 4 helper waves); 256 blocks -> 1 block/CU
    // -> 8 waves/CU -> 2 waves/SIMD (one rec + one helper per SIMD).
    rnn_kernel<<<dim3(B_TOTAL / 32), dim3(512), 0, stream>>>(
        x, Wih, Whh, bih, bhh, Wfc, bfc, out);
}

// Round 4
// 230.722 us; speedup vs baseline: 1.0441x; 1.0441x over previous
//
#include <hip/hip_runtime.h>
#include <stdint.h>

// RNN: h_t = tanh(x_t W_ih^T + b_ih + b_hh + h_{t-1} W_hh^T)
// out[b,t] = W_fc . h_t + b_fc ;  hidden = h_T.  B=8192, T=512, I=H=7. fp32.
//
// R10: decoupled producer-consumer. R9 (104 us vs R6's 68.5) conserved VALU
// busy-time (33%x104 = 47%x68.5) but added stall: (a) helper loaded x in the
// same slot it consumed it (zero prefetch distance -> full L3/HBM latency on
// the slot critical path), (b) one barrier domain spanned 8 waves in lockstep.
// Fix: 128-thread blocks (1 rec wave + 1 helper wave, 8 chains), 1024 blocks
// -> 4 independently-paced blocks/CU (skew in one block absorbed by the other
// three), and register prefetch distance 1: helper consumes xa (chunk t+1,
// loaded last slot) then reloads xa with chunk t+2. Plain HIP loads, plain
// __syncthreads (2-wave barrier domain), no inline asm.
// Slot t: rec computes h(t) from lds_u[t&1] -> lds_h[t&1];
//         helper: u(t+1)=Wih.xa -> lds_u[(t+1)&1]; xa <- chunk t+2;
//                 out(t-1) from lds_h[(t-1)&1]. All parities disjoint.

#define B_TOTAL 8192
#define T_STEPS 512

#define DPP_QUAD0 0x00        // quad_perm [0,0,0,0]
#define DPP_QUAD1 0x55        // quad_perm [1,1,1,1]
#define DPP_QUAD2 0xAA        // quad_perm [2,2,2,2]
#define DPP_QUAD3 0xFF        // quad_perm [3,3,3,3]
#define DPP_XOR1  0xB1        // quad_perm [1,0,3,2]
#define DPP_XOR2  0x4E        // quad_perm [2,3,0,1]
#define DPP_HM    0x141       // row_half_mirror

template <int CTRL>
__device__ __forceinline__ float dpp_mov(float v) {
    int s = __float_as_int(v);
    return __int_as_float(__builtin_amdgcn_update_dpp(s, s, CTRL, 0xF, 0xF, true));
}

__device__ __forceinline__ float tanh_fast(float a) {
    float e = __builtin_amdgcn_exp2f(a * 2.8853900817779268f);
    float r = __builtin_amdgcn_rcpf(e + 1.0f);
    return __builtin_fmaf(-2.0f, r, 1.0f);
}

__global__ __launch_bounds__(128, 2) void rnn_kernel(
    const float* __restrict__ x,    // [B, T, I]
    const float* __restrict__ Wih,  // [H, I]
    const float* __restrict__ Whh,  // [H, H]
    const float* __restrict__ bih,  // [H]
    const float* __restrict__ bhh,  // [H]
    const float* __restrict__ Wfc,  // [1, H]
    const float* __restrict__ bfc,  // [1]
    float* __restrict__ out)        // [B*T] out, then [B*H] hidden
{
    const int tid   = threadIdx.x;
    const int role  = tid >> 6;         // wave 0 = recurrence, wave 1 = helper
    const int lane  = tid & 63;
    const int k     = lane & 7;         // h-row (7 = dummy)
    const int b     = blockIdx.x * 8 + (lane >> 3);
    const int lbase = lane * 10;        // stride 10: 8B-aligned, 2-way banks (free)

    // [parity][lane*10 + s]; 5120 B each, 10240 B total per block.
    __shared__ __attribute__((aligned(16))) float lds_u[2][640];
    __shared__ __attribute__((aligned(16))) float lds_h[2][640];

    // ---- per-role persistent state ----
    float wa[4] = {0.f, 0.f, 0.f, 0.f}, wb[4] = {0.f, 0.f, 0.f, 0.f};
    float ra0 = 0.f, ra1 = 0.f, ra2 = 0.f, ra3 = 0.f;
    float rb0 = 0.f, rb1 = 0.f, rb2 = 0.f, rb3 = 0.f;
    float wih[7] = {0.f, 0.f, 0.f, 0.f, 0.f, 0.f, 0.f};
    float bias = 0.f, wfc_own = 0.f, bfcv = 0.f;
    const float* xrow = x + (size_t)b * (T_STEPS * 7);   // 3584 floats, 16B-aligned
    float* outp = out + (size_t)b * T_STEPS;
    float4 xa[14];                       // helper: prefetched chunk (56 floats)

    // u-projection of 56 floats in xb -> lds_u[par].
    auto u_store = [&](const float4* xb, int par) {
        float xv[56];
        #pragma unroll
        for (int i = 0; i < 14; ++i) {
            xv[4 * i + 0] = xb[i].x; xv[4 * i + 1] = xb[i].y;
            xv[4 * i + 2] = xb[i].z; xv[4 * i + 3] = xb[i].w;
        }
        float u[8];
        #pragma unroll
        for (int s = 0; s < 8; ++s) {
            const float* xs = &xv[s * 7];
            float p01 = __builtin_fmaf(wih[1], xs[1], wih[0] * xs[0]);
            float p23 = __builtin_fmaf(wih[3], xs[3], wih[2] * xs[2]);
            float p45 = __builtin_fmaf(wih[5], xs[5], wih[4] * xs[4]);
            float p6b = __builtin_fmaf(wih[6], xs[6], bias);
            u[s] = (p01 + p23) + (p45 + p6b);
        }
        float2* up = (float2*)&lds_u[par][lbase];
        up[0] = make_float2(u[0], u[1]);
        up[1] = make_float2(u[2], u[3]);
        up[2] = make_float2(u[4], u[5]);
        up[3] = make_float2(u[6], u[7]);
    };

    // Out-projection butterfly for chunk t from lds_h, store 8 outputs.
    auto emit_out = [&](int t) {
        const float2* hp = (const float2*)&lds_h[t & 1][lbase];
        float2 h01 = hp[0], h23 = hp[1], h45 = hp[2], h67 = hp[3];
        float hs[8] = {h01.x, h01.y, h23.x, h23.y, h45.x, h45.y, h67.x, h67.y};
        float o[8];
        #pragma unroll
        for (int s = 0; s < 8; ++s) {
            float v = wfc_own * hs[s];
            v += dpp_mov<DPP_XOR1>(v);
            v += dpp_mov<DPP_XOR2>(v);
            v += dpp_mov<DPP_HM>(v);
            o[s] = v + bfcv;
        }
        if (k == 7) {
            *(float4*)(outp + t * 8 + 0) = make_float4(o[0], o[1], o[2], o[3]);
            *(float4*)(outp + t * 8 + 4) = make_float4(o[4], o[5], o[6], o[7]);
        }
    };

    // 8-step serial recurrence on lds_u[par] -> lds_h[par].
    auto rec_step = [&](int par) {
        const float2* up = (const float2*)&lds_u[par][lbase];
        float2 u01 = up[0], u23 = up[1], u45 = up[2], u67 = up[3];
        float u[8] = {u01.x, u01.y, u23.x, u23.y, u45.x, u45.y, u67.x, u67.y};
        float hs[8];
        #pragma unroll
        for (int s = 0; s < 8; ++s) {
            float p0 = __builtin_fmaf(wa[0], ra0, u[s]);
            float p1 = __builtin_fmaf(wa[2], ra2, wa[1] * ra1);
            float p2 = __builtin_fmaf(wb[0], rb0, wa[3] * ra3);
            float p3 = __builtin_fmaf(wb[2], rb2, wb[1] * rb1);
            float p4 = wb[3] * rb3;
            float acc = (p0 + p1) + (p2 + (p3 + p4));
            float hk = tanh_fast(acc);
            hs[s] = hk;
            ra0 = dpp_mov<DPP_QUAD0>(hk);
            ra1 = dpp_mov<DPP_QUAD1>(hk);
            ra2 = dpp_mov<DPP_QUAD2>(hk);
            ra3 = dpp_mov<DPP_QUAD3>(hk);
            rb0 = dpp_mov<DPP_HM>(ra0);
            rb1 = dpp_mov<DPP_HM>(ra1);
            rb2 = dpp_mov<DPP_HM>(ra2);
            rb3 = dpp_mov<DPP_HM>(ra3);
        }
        float2* hp = (float2*)&lds_h[par][lbase];
        hp[0] = make_float2(hs[0], hs[1]);
        hp[1] = make_float2(hs[2], hs[3]);
        hp[2] = make_float2(hs[4], hs[5]);
        hp[3] = make_float2(hs[6], hs[7]);
    };

    // ---- role-divergent prologue (no barriers inside) ----
    if (role == 0) {
        const int quad = (lane >> 2) & 1;
        float whh_row[8];
        #pragma unroll
        for (int i = 0; i < 8; ++i) whh_row[i] = 0.0f;
        if (k < 7) {
            #pragma unroll
            for (int i = 0; i < 7; ++i) whh_row[i] = Whh[k * 7 + i];
        }
        #pragma unroll
        for (int j = 0; j < 4; ++j) {
            wa[j] = quad ? whh_row[4 + j] : whh_row[j];
            wb[j] = quad ? whh_row[j]     : whh_row[4 + j];
        }
    } else {
        if (k < 7) {
            #pragma unroll
            for (int i = 0; i < 7; ++i) wih[i] = Wih[k * 7 + i];
            bias = bih[k] + bhh[k];
            wfc_own = Wfc[k];
        }
        bfcv = bfc[0];
        // chunk 0 -> u(0) directly; chunk 1 -> xa (consumed at slot 0).
        float4 x0[14];
        const float4* s0 = (const float4*)xrow;
        #pragma unroll
        for (int i = 0; i < 14; ++i) x0[i] = s0[i];
        u_store(x0, 0);
        const float4* s1 = (const float4*)(xrow + 56);
        #pragma unroll
        for (int i = 0; i < 14; ++i) xa[i] = s1[i];
    }
    __syncthreads();                     // b0: u(0) ready

    // Slot t (one uniform barrier each):
    //   rec:    h(t) from u(t)          [parity t&1]
    //   helper: u(t+1) from xa -> LDS   [parity (t+1)&1]; xa <- chunk t+2;
    //           out(t-1) from h(t-1)    [parity (t-1)&1]
    #pragma unroll 1
    for (int t = 0; t < 64; ++t) {
        if (role == 0) {
            rec_step(t & 1);
        } else {
            if (t < 63) {
                u_store(xa, (t + 1) & 1);            // consumes xa (chunk t+1)
                const int nc = (t + 2 <= 63) ? (t + 2) : 0;   // dummy=chunk0
                const float4* src = (const float4*)(xrow + nc * 56);
                #pragma unroll
                for (int i = 0; i < 14; ++i) xa[i] = src[i];  // in flight to t+1
            }
            if (t > 0) emit_out(t - 1);
        }
        __syncthreads();
    }

    // ---- epilogue (after final barrier; no more barriers) ----
    if (role == 0) {
        // hidden h_T: lane k's own value is ra_{k&3} (both quads)
        if (k < 7) {
            int kk = k & 3;
            float hv = (kk == 0) ? ra0 : (kk == 1) ? ra1 : (kk == 2) ? ra2 : ra3;
            out[(size_t)B_TOTAL * T_STEPS + (size_t)b * 7 + k] = hv;
        }
    } else {
        emit_out(63);                    // h(63) written before final barrier
    }
}

extern "C" void kernel_launch(void* const* d_in, const int* in_sizes, int n_in,
                              void* d_out, int out_size, void* d_ws, size_t ws_size,
                              hipStream_t stream) {
    const float* x   = (const float*)d_in[0];
    const float* Wih = (const float*)d_in[1];
    const float* Whh = (const float*)d_in[2];
    const float* bih = (const float*)d_in[3];
    const float* bhh = (const float*)d_in[4];
    const float* Wfc = (const float*)d_in[5];
    const float* bfc = (const float*)d_in[6];
    float* out = (float*)d_out;

    // 8 chains/block (1 rec + 1 helper wave); 1024 blocks -> 4 blocks/CU
    // -> 8 waves/CU -> 2 waves/SIMD, with 4 independent barrier domains/CU.
    rnn_kernel<<<dim3(B_TOTAL / 8), dim3(128), 0, stream>>>(
        x, Wih, Whh, bih, bhh, Wfc, bfc, out);
}

// Round 5
// 208.020 us; speedup vs baseline: 1.1580x; 1.1091x over previous
//
#include <hip/hip_runtime.h>
#include <stdint.h>

// RNN: h_t = tanh(x_t W_ih^T + b_ih + b_hh + h_{t-1} W_hh^T)
// out[b,t] = W_fc . h_t + b_fc ;  hidden = h_T.  B=8192, T=512, I=H=7. fp32.
//
// R11: R6 topology (single self-sufficient wave, 8 lanes/chain, asm prefetch,
// no barriers) + critical-path algebra. R9/R10 proved the wall is the
// per-chain serial chain (512 x ~320cyc; VALU busy-time conserved across all
// topologies), so shorten the loop-carried chain:
//   h = 1 - 2r, r = 1/(e^{cz}+1), c = 2/ln2.
//   z = u + W.h = (u + W.1) - 2 W.r  ->  carry r, fold c and -2c into
//   bias/weights. Step chain: tree(+u') -> exp2 -> add1 -> rcp  (the mul
//   before exp2 and the fma after rcp are GONE: 11 -> 9 dependent ops).
// Out-proj: sum wfc.h = (bfc + sum wfc) - 2 sum wfc.r -> butterfly on -2wfc.r
// with a prologue-computed constant. Hidden h_T: fma(-2, r, 1) once at end.

#define B_TOTAL 8192
#define T_STEPS 512

#define DPP_QUAD0 0x00        // quad_perm [0,0,0,0]
#define DPP_QUAD1 0x55        // quad_perm [1,1,1,1]
#define DPP_QUAD2 0xAA        // quad_perm [2,2,2,2]
#define DPP_QUAD3 0xFF        // quad_perm [3,3,3,3]
#define DPP_XOR1  0xB1        // quad_perm [1,0,3,2]
#define DPP_XOR2  0x4E        // quad_perm [2,3,0,1]
#define DPP_HM    0x141       // row_half_mirror

template <int CTRL>
__device__ __forceinline__ float dpp_mov(float v) {
    int s = __float_as_int(v);
    return __int_as_float(__builtin_amdgcn_update_dpp(s, s, CTRL, 0xF, 0xF, true));
}

typedef float v4f __attribute__((ext_vector_type(4)));

struct XChunk { v4f v[14]; };   // 8 steps * 7 floats = 56 floats = 224 B

// Issue 14 async 16B loads; results land in the asm-def'd VGPRs at vmcnt.
__device__ __forceinline__ void chunk_issue(XChunk& ch, const float* base) {
    #pragma unroll
    for (int i = 0; i < 14; ++i)
        asm volatile("global_load_dwordx4 %0, %1, off offset:%2"
                     : "=v"(ch.v[i]) : "v"(base), "i"(16 * i));
}

// Wait until at most N VMEM ops outstanding; "+v" operands force ordering
// (asm is a use+def of every buffer register -> compiler cannot hoist uses).
#define CHUNK_WAIT(ch, N)                                                     \
    asm volatile("s_waitcnt vmcnt(" #N ")"                                    \
        : "+v"((ch).v[0]), "+v"((ch).v[1]), "+v"((ch).v[2]), "+v"((ch).v[3]), \
          "+v"((ch).v[4]), "+v"((ch).v[5]), "+v"((ch).v[6]), "+v"((ch).v[7]), \
          "+v"((ch).v[8]), "+v"((ch).v[9]), "+v"((ch).v[10]),                 \
          "+v"((ch).v[11]), "+v"((ch).v[12]), "+v"((ch).v[13]))

__global__ __launch_bounds__(256, 1) void rnn_kernel(
    const float* __restrict__ x,    // [B, T, I]
    const float* __restrict__ Wih,  // [H, I]
    const float* __restrict__ Whh,  // [H, H]
    const float* __restrict__ bih,  // [H]
    const float* __restrict__ bhh,  // [H]
    const float* __restrict__ Wfc,  // [1, H]
    const float* __restrict__ bfc,  // [1]
    float* __restrict__ out)        // [B*T] out, then [B*H] hidden
{
    const int tid  = threadIdx.x;
    const int k    = tid & 7;                 // h-row (7 = dummy)
    const int b    = blockIdx.x * 32 + (tid >> 3);
    const int quad = (tid >> 2) & 1;

    const float C2L = 2.8853900817779268f;    // 2/ln2

    // ---- weights first (compiler loads + its own waitcnts happen here,
    // BEFORE any asm prefetch is outstanding) ----
    float wih[7];                 // pre-scaled by c
    float wa[4], wb[4];           // pre-scaled by -2c
    float bias = 0.0f;            // c*(bih+bhh+sum_j Whh[k][j])
    float wfcm2 = 0.0f;           // -2*wfc[k]
    float obase;                  // bfc + sum_k wfc[k]
    {
        float whh_row[8];
        #pragma unroll
        for (int i = 0; i < 8; ++i) whh_row[i] = 0.0f;
        float wfc_own = 0.0f;
        if (k < 7) {
            float srow = 0.0f;
            #pragma unroll
            for (int i = 0; i < 7; ++i) {
                float wr = Whh[k * 7 + i];
                whh_row[i] = -2.0f * C2L * wr;
                srow += wr;
                wih[i] = C2L * Wih[k * 7 + i];
            }
            bias = C2L * (bih[k] + bhh[k] + srow);
            wfc_own = Wfc[k];
        } else {
            #pragma unroll
            for (int i = 0; i < 7; ++i) wih[i] = 0.0f;
        }
        wfcm2 = -2.0f * wfc_own;
        // prologue butterfly: sum of wfc over the 8-lane group (row7 = 0)
        float ws = wfc_own;
        ws += dpp_mov<DPP_XOR1>(ws);
        ws += dpp_mov<DPP_XOR2>(ws);
        ws += dpp_mov<DPP_HM>(ws);
        obase = bfc[0] + ws;
        #pragma unroll
        for (int j = 0; j < 4; ++j) {
            wa[j] = quad ? whh_row[4 + j] : whh_row[j];
            wb[j] = quad ? whh_row[j]     : whh_row[4 + j];
        }
    }

    const float* xrow = x + (size_t)b * (T_STEPS * 7);   // 3584 floats
    float* outp = out + (size_t)b * T_STEPS;

    // state = broadcasts of r (h = 1 - 2r); h0 = 0 <=> r0 = 0.5
    float a0 = 0.5f, a1 = 0.5f, a2 = 0.5f, a3 = 0.5f;
    float b0 = 0.5f, b1 = 0.5f, b2 = 0.5f, b3 = 0.5f;

    XChunk A, B;
    chunk_issue(A, xrow);            // chunk 0
    chunk_issue(B, xrow + 56);       // chunk 1

    // Process one ready 8-step chunk; optionally reissue its buffer with the
    // chunk-ahead reload right after the u-extraction consumes it.
    auto do_chunk = [&](XChunk& buf, int c, const float* reload) {
        float u[8];
        {
            float xv[56];
            #pragma unroll
            for (int i = 0; i < 14; ++i) {
                xv[4 * i + 0] = buf.v[i].x; xv[4 * i + 1] = buf.v[i].y;
                xv[4 * i + 2] = buf.v[i].z; xv[4 * i + 3] = buf.v[i].w;
            }
            #pragma unroll
            for (int s = 0; s < 8; ++s) {
                const float* xs = &xv[s * 7];
                float p01 = __builtin_fmaf(wih[1], xs[1], wih[0] * xs[0]);
                float p23 = __builtin_fmaf(wih[3], xs[3], wih[2] * xs[2]);
                float p45 = __builtin_fmaf(wih[5], xs[5], wih[4] * xs[4]);
                float p6b = __builtin_fmaf(wih[6], xs[6], bias);
                u[s] = (p01 + p23) + (p45 + p6b);
            }
        }
        if (reload) chunk_issue(buf, reload);   // in flight across the 8 steps
        // Serial recurrence on r (b-values consumed last in the tree)
        float rs[8];
        #pragma unroll
        for (int s = 0; s < 8; ++s) {
            float p0 = __builtin_fmaf(wa[0], a0, u[s]);
            float p1 = __builtin_fmaf(wa[2], a2, wa[1] * a1);
            float p2 = __builtin_fmaf(wb[0], b0, wa[3] * a3);
            float p3 = __builtin_fmaf(wb[2], b2, wb[1] * b1);
            float p4 = wb[3] * b3;
            float acc = (p0 + p1) + (p2 + (p3 + p4));
            float e  = __builtin_amdgcn_exp2f(acc);
            float rk = __builtin_amdgcn_rcpf(e + 1.0f);
            rs[s] = rk;
            a0 = dpp_mov<DPP_QUAD0>(rk);
            a1 = dpp_mov<DPP_QUAD1>(rk);
            a2 = dpp_mov<DPP_QUAD2>(rk);
            a3 = dpp_mov<DPP_QUAD3>(rk);
            b0 = dpp_mov<DPP_HM>(a0);
            b1 = dpp_mov<DPP_HM>(a1);
            b2 = dpp_mov<DPP_HM>(a2);
            b3 = dpp_mov<DPP_HM>(a3);
        }
        // Out-projection butterfly on -2*wfc*r (ILP filler); add folded const
        float o[8];
        #pragma unroll
        for (int s = 0; s < 8; ++s) {
            float v = wfcm2 * rs[s];
            v += dpp_mov<DPP_XOR1>(v);
            v += dpp_mov<DPP_XOR2>(v);
            v += dpp_mov<DPP_HM>(v);
            o[s] = v + obase;
        }
        if (k == 7) {
            *(float4*)(outp + c * 8 + 0) = make_float4(o[0], o[1], o[2], o[3]);
            *(float4*)(outp + c * 8 + 4) = make_float4(o[4], o[5], o[6], o[7]);
        }
    };

    // Steady loop: chunks 0..61; reloads c+2 (<=62) and c+3 (<=63) always valid.
    #pragma unroll 1
    for (int c = 0; c < 62; c += 2) {
        CHUNK_WAIT(A, 14);                         // A(c) is oldest -> drained
        do_chunk(A, c, xrow + (c + 2) * 56);
        CHUNK_WAIT(B, 14);                         // B(c+1) oldest -> drained
        do_chunk(B, c + 1, xrow + (c + 3) * 56);
    }
    // Epilogue: chunks 62 (A) and 63 (B), no reloads.
    CHUNK_WAIT(A, 14);
    do_chunk(A, 62, nullptr);
    CHUNK_WAIT(B, 0);
    do_chunk(B, 63, nullptr);

    // hidden h_T: lane k's own r is a_{k&3} (both quads); h = 1 - 2r
    if (k < 7) {
        int kk = k & 3;
        float rv = (kk == 0) ? a0 : (kk == 1) ? a1 : (kk == 2) ? a2 : a3;
        out[(size_t)B_TOTAL * T_STEPS + (size_t)b * 7 + k] =
            __builtin_fmaf(-2.0f, rv, 1.0f);
    }
}

extern "C" void kernel_launch(void* const* d_in, const int* in_sizes, int n_in,
                              void* d_out, int out_size, void* d_ws, size_t ws_size,
                              hipStream_t stream) {
    const float* x   = (const float*)d_in[0];
    const float* Wih = (const float*)d_in[1];
    const float* Whh = (const float*)d_in[2];
    const float* bih = (const float*)d_in[3];
    const float* bhh = (const float*)d_in[4];
    const float* Wfc = (const float*)d_in[5];
    const float* bfc = (const float*)d_in[6];
    float* out = (float*)d_out;

    // 8192 chains * 8 lanes = 65536 threads; 256/block -> 256 blocks (1/CU),
    // 4 waves/block spread over the 4 SIMDs -> 1 wave/SIMD chip-wide.
    rnn_kernel<<<dim3(B_TOTAL / 32), dim3(256), 0, stream>>>(
        x, Wih, Whh, bih, bhh, Wfc, bfc, out);
}